// Round 2
// baseline (104.254 us; speedup 1.0000x reference)
//
#include <hip/hip_runtime.h>
#include <cfloat>

#define NB 4096
#define NE 64
#define NH 512
#define TOPK 8
#define GRID 512
#define ROWS_PER_BLOCK (NB / GRID)   // 8 rows/block, 4 waves -> 2 rows/wave

__global__ __launch_bounds__(256) void moe_router_fused(
    const float* __restrict__ x_context,  // (B,68)
    const float* __restrict__ x_q,        // (B,E,3)
    const float* __restrict__ x_r,        // (B,E,2)
    const float* __restrict__ x_k,        // (B,E,2)
    const float* __restrict__ Wc,         // (68,512)
    const float* __restrict__ bc,         // (512)
    const float* __restrict__ We,         // (7,512)
    const float* __restrict__ be,         // (512)
    const float* __restrict__ Ws,         // (1024)
    const float* __restrict__ bs,         // (1)
    float* __restrict__ out_action,       // (B,3)
    float* __restrict__ out_gate,         // (B,E)
    float* __restrict__ out_logits)       // (B,E)
{
    // scoef: [0..6] = We@Ws_e, [7..74] = Wc@Ws_c, [75] = be@Ws_e + bc@Ws_c + bs
    __shared__ float scoef[76];
    __shared__ __align__(16) float sval[4][64];

    int t = threadIdx.x;

    // ---- prologue: fold H=512 away (linearity of the logit in the encodings) ----
    if (t < 76) {
        float acc = 0.f;
        if (t < 7) {
            const float4* row = (const float4*)(We + t * NH);
            const float4* wv  = (const float4*)(Ws);
            #pragma unroll 8
            for (int i = 0; i < NH / 4; ++i) {
                float4 a = row[i], b = wv[i];
                acc += a.x*b.x + a.y*b.y + a.z*b.z + a.w*b.w;
            }
        } else if (t < 75) {
            const float4* row = (const float4*)(Wc + (size_t)(t - 7) * NH);
            const float4* wv  = (const float4*)(Ws + NH);
            #pragma unroll 8
            for (int i = 0; i < NH / 4; ++i) {
                float4 a = row[i], b = wv[i];
                acc += a.x*b.x + a.y*b.y + a.z*b.z + a.w*b.w;
            }
        } else {
            const float4* b4  = (const float4*)be;
            const float4* c4  = (const float4*)bc;
            const float4* we4 = (const float4*)Ws;
            const float4* wc4 = (const float4*)(Ws + NH);
            #pragma unroll 8
            for (int i = 0; i < NH / 4; ++i) {
                float4 a = b4[i], w0 = we4[i], c = c4[i], w1 = wc4[i];
                acc += a.x*w0.x + a.y*w0.y + a.z*w0.z + a.w*w0.w
                     + c.x*w1.x + c.y*w1.y + c.z*w1.z + c.w*w1.w;
            }
            acc += bs[0];
        }
        scoef[t] = acc;
    }
    __syncthreads();

    int lane = t & 63;
    int w    = t >> 6;
    float* sc = sval[w];   // per-wave private strip: no cross-wave sync needed

    int b0 = blockIdx.x * ROWS_PER_BLOCK;
    #pragma unroll
    for (int it = 0; it < ROWS_PER_BLOCK / 4; ++it) {
        int b = b0 + it * 4 + w;

        // context contribution: dot(x_context[b,:68], v_c)
        const float* xc = x_context + (size_t)b * 68;
        float cb = xc[lane] * scoef[7 + lane];
        if (lane < 4) cb += xc[64 + lane] * scoef[71 + lane];
        #pragma unroll
        for (int off = 32; off; off >>= 1) cb += __shfl_xor(cb, off);

        size_t be_idx = (size_t)b * NE + lane;
        float q0 = x_q[be_idx * 3 + 0];
        float q1 = x_q[be_idx * 3 + 1];
        float q2 = x_q[be_idx * 3 + 2];
        float r0 = x_r[be_idx * 2 + 0];
        float r1 = x_r[be_idx * 2 + 1];
        float k0 = x_k[be_idx * 2 + 0];
        float k1 = x_k[be_idx * 2 + 1];

        float logit = q0 * scoef[0] + q1 * scoef[1] + q2 * scoef[2]
                    + r0 * scoef[3] + r1 * scoef[4]
                    + k0 * scoef[5] + k1 * scoef[6]
                    + scoef[75] + cb;

        out_logits[be_idx] = logit;

        // rank-based top-8: lane selected iff fewer than 8 lanes beat it
        // (strictly greater, or equal with smaller index == lax.top_k tie-break)
        sc[lane] = logit;  // intra-wave LDS write->read: DS pipe is in-order per wave
        float m = -FLT_MAX;
        int rank = 0;
        #pragma unroll
        for (int j = 0; j < 64; j += 4) {
            float4 v = *(const float4*)(sc + j);   // same-address broadcast, conflict-free
            rank += (v.x > logit || (v.x == logit && (j + 0) < lane)) ? 1 : 0;
            rank += (v.y > logit || (v.y == logit && (j + 1) < lane)) ? 1 : 0;
            rank += (v.z > logit || (v.z == logit && (j + 2) < lane)) ? 1 : 0;
            rank += (v.w > logit || (v.w == logit && (j + 3) < lane)) ? 1 : 0;
            m = fmaxf(m, fmaxf(fmaxf(v.x, v.y), fmaxf(v.z, v.w)));
        }

        // softmax over selected lanes; non-selected are exactly 0 (== exp(-inf))
        float e = (rank < TOPK) ? __expf(logit - m) : 0.f;
        float d  = e;
        float a0 = e * q0, a1 = e * q1, a2 = e * q2;
        #pragma unroll
        for (int off = 32; off; off >>= 1) {
            d  += __shfl_xor(d,  off);
            a0 += __shfl_xor(a0, off);
            a1 += __shfl_xor(a1, off);
            a2 += __shfl_xor(a2, off);
        }
        out_gate[be_idx] = e / d;
        if (lane == 0) {
            float inv = 1.f / d;   // action = (sum e*q) / denom == sum gate*q
            out_action[(size_t)b * 3 + 0] = a0 * inv;
            out_action[(size_t)b * 3 + 1] = a1 * inv;
            out_action[(size_t)b * 3 + 2] = a2 * inv;
        }
    }
}

extern "C" void kernel_launch(void* const* d_in, const int* in_sizes, int n_in,
                              void* d_out, int out_size, void* d_ws, size_t ws_size,
                              hipStream_t stream) {
    const float* x_context = (const float*)d_in[0];
    const float* x_q       = (const float*)d_in[1];
    const float* x_r       = (const float*)d_in[2];
    const float* x_k       = (const float*)d_in[3];
    const float* Wc        = (const float*)d_in[4];
    const float* bc        = (const float*)d_in[5];
    const float* We        = (const float*)d_in[6];
    const float* be        = (const float*)d_in[7];
    const float* Ws        = (const float*)d_in[8];
    const float* bs        = (const float*)d_in[9];

    float* out        = (float*)d_out;
    float* out_action = out;                    // B*3
    float* out_gate   = out + NB * 3;           // B*E
    float* out_logits = out + NB * 3 + NB * NE; // B*E

    moe_router_fused<<<GRID, 256, 0, stream>>>(
        x_context, x_q, x_r, x_k, Wc, bc, We, be, Ws, bs,
        out_action, out_gate, out_logits);
}

// Round 3
// 84.577 us; speedup vs baseline: 1.2327x; 1.2327x over previous
//
#include <hip/hip_runtime.h>
#include <cfloat>

#define NB 4096
#define NE 64
#define NH 512
#define TOPK 8

// Workspace layout (floats): [0..6] v_e (We @ Ws_e), [7..74] v_c (Wc @ Ws_c),
// [75] s_total = be@Ws_e + bc@Ws_c + bs
__global__ void precompute_kernel(const float* __restrict__ Wc,
                                  const float* __restrict__ bc,
                                  const float* __restrict__ We,
                                  const float* __restrict__ be,
                                  const float* __restrict__ Ws,
                                  const float* __restrict__ bs,
                                  float* __restrict__ ws) {
    int r = blockIdx.x;      // 0..75 : which reduction
    int lane = threadIdx.x;  // 0..63
    float partial = 0.f;
    if (r < 7) {
        const float* row = We + r * NH;
        for (int h = lane; h < NH; h += 64) partial += row[h] * Ws[h];
    } else if (r < 75) {
        const float* row = Wc + (size_t)(r - 7) * NH;
        for (int h = lane; h < NH; h += 64) partial += row[h] * Ws[NH + h];
    } else {
        for (int h = lane; h < NH; h += 64)
            partial += be[h] * Ws[h] + bc[h] * Ws[NH + h];
    }
    #pragma unroll
    for (int off = 32; off; off >>= 1) partial += __shfl_xor(partial, off);
    if (lane == 0) {
        if (r == 75) partial += bs[0];
        ws[r] = partial;
    }
}

// One 64-lane wave per batch row; lane e owns expert e.
__global__ __launch_bounds__(256) void router_kernel(
    const float* __restrict__ x_context,  // (B,68)
    const float* __restrict__ x_q,        // (B,E,3)
    const float* __restrict__ x_r,        // (B,E,2)
    const float* __restrict__ x_k,        // (B,E,2)
    const float* __restrict__ ws,         // 76 precomputed floats
    float* __restrict__ out_action,       // (B,3)
    float* __restrict__ out_gate,         // (B,E)
    float* __restrict__ out_logits)       // (B,E)
{
    __shared__ float scoef[76];
    __shared__ __align__(16) float sval[4][64];
    int t = threadIdx.x;
    if (t < 76) scoef[t] = ws[t];
    __syncthreads();

    int lane = t & 63;
    int w = t >> 6;
    float* sc = sval[w];   // per-wave private strip, no cross-wave sync needed
    int b = blockIdx.x * 4 + w;

    // context contribution: dot(x_context[b,:68], v_c)
    const float* xc = x_context + (size_t)b * 68;
    float cb = xc[lane] * scoef[7 + lane];
    if (lane < 4) cb += xc[64 + lane] * scoef[71 + lane];
    #pragma unroll
    for (int off = 32; off; off >>= 1) cb += __shfl_xor(cb, off);

    size_t be_idx = (size_t)b * NE + lane;
    float q0 = x_q[be_idx * 3 + 0];
    float q1 = x_q[be_idx * 3 + 1];
    float q2 = x_q[be_idx * 3 + 2];
    float r0 = x_r[be_idx * 2 + 0];
    float r1 = x_r[be_idx * 2 + 1];
    float k0 = x_k[be_idx * 2 + 0];
    float k1 = x_k[be_idx * 2 + 1];

    float logit = q0 * scoef[0] + q1 * scoef[1] + q2 * scoef[2]
                + r0 * scoef[3] + r1 * scoef[4]
                + k0 * scoef[5] + k1 * scoef[6]
                + scoef[75] + cb;

    out_logits[be_idx] = logit;

    // rank-based top-8: lane selected iff fewer than 8 lanes beat it
    // (strictly greater, or equal with smaller index == lax.top_k tie-break)
    sc[lane] = logit;
    float m = -FLT_MAX;
    int rank = 0;
    #pragma unroll
    for (int j = 0; j < 64; j += 4) {
        float4 v = *(const float4*)(sc + j);   // same-address broadcast, conflict-free
        rank += (v.x > logit || (v.x == logit && (j + 0) < lane)) ? 1 : 0;
        rank += (v.y > logit || (v.y == logit && (j + 1) < lane)) ? 1 : 0;
        rank += (v.z > logit || (v.z == logit && (j + 2) < lane)) ? 1 : 0;
        rank += (v.w > logit || (v.w == logit && (j + 3) < lane)) ? 1 : 0;
        m = fmaxf(m, fmaxf(fmaxf(v.x, v.y), fmaxf(v.z, v.w)));
    }

    // softmax over selected lanes; non-selected are exactly 0 (== exp(-inf))
    float e = (rank < TOPK) ? __expf(logit - m) : 0.f;
    float d  = e;
    float a0 = e * q0, a1 = e * q1, a2 = e * q2;
    #pragma unroll
    for (int off = 32; off; off >>= 1) {
        d  += __shfl_xor(d,  off);
        a0 += __shfl_xor(a0, off);
        a1 += __shfl_xor(a1, off);
        a2 += __shfl_xor(a2, off);
    }
    out_gate[be_idx] = e / d;
    if (lane == 0) {
        float inv = 1.f / d;   // action = (sum e*q)/denom == sum gate*q
        out_action[(size_t)b * 3 + 0] = a0 * inv;
        out_action[(size_t)b * 3 + 1] = a1 * inv;
        out_action[(size_t)b * 3 + 2] = a2 * inv;
    }
}

extern "C" void kernel_launch(void* const* d_in, const int* in_sizes, int n_in,
                              void* d_out, int out_size, void* d_ws, size_t ws_size,
                              hipStream_t stream) {
    const float* x_context = (const float*)d_in[0];
    const float* x_q       = (const float*)d_in[1];
    const float* x_r       = (const float*)d_in[2];
    const float* x_k       = (const float*)d_in[3];
    const float* Wc        = (const float*)d_in[4];
    const float* bc        = (const float*)d_in[5];
    const float* We        = (const float*)d_in[6];
    const float* be        = (const float*)d_in[7];
    const float* Ws        = (const float*)d_in[8];
    const float* bs        = (const float*)d_in[9];

    float* out        = (float*)d_out;
    float* out_action = out;                    // B*3
    float* out_gate   = out + NB * 3;           // B*E
    float* out_logits = out + NB * 3 + NB * NE; // B*E
    float* wsf = (float*)d_ws;

    precompute_kernel<<<76, 64, 0, stream>>>(Wc, bc, We, be, Ws, bs, wsf);
    router_kernel<<<NB / 4, 256, 0, stream>>>(x_context, x_q, x_r, x_k, wsf,
                                              out_action, out_gate, out_logits);
}